// Round 11
// baseline (1383.904 us; speedup 1.0000x reference)
//
#include <hip/hip_runtime.h>
#include <hip/hip_bf16.h>
#include <math.h>

#define TEMP 0.1

typedef float f4 __attribute__((ext_vector_type(4)));
typedef short s8v __attribute__((ext_vector_type(8)));
typedef int   i4v __attribute__((ext_vector_type(4)));

__device__ inline short f2bf(float f) {
    __hip_bfloat16 h = __float2bfloat16(f);
    return *reinterpret_cast<short*>(&h);
}
__device__ inline float bf2f(short s) {
    __hip_bfloat16 h = *reinterpret_cast<__hip_bfloat16*>(&s);
    return __bfloat162float(h);
}

// ---------- quantize rows of length 1024 to 5 balanced int8 limbs (R5-proven) ----------
__global__ __launch_bounds__(256) void quantize_rows(
    const float* __restrict__ src, signed char* __restrict__ limbs,
    long plane_stride, double* __restrict__ scale)
{
    const int row = blockIdx.x, tid = threadIdx.x;
    const float4 v = ((const float4*)(src + (size_t)row * 1024))[tid];
    float m = fmaxf(fmaxf(fabsf(v.x), fabsf(v.y)), fmaxf(fabsf(v.z), fabsf(v.w)));
#pragma unroll
    for (int off = 32; off > 0; off >>= 1) m = fmaxf(m, __shfl_down(m, off));
    __shared__ float wmax[4];
    __shared__ int ssig;
    if ((tid & 63) == 0) wmax[tid >> 6] = m;
    __syncthreads();
    if (tid == 0) {
        float rm = fmaxf(fmaxf(wmax[0], wmax[1]), fmaxf(wmax[2], wmax[3]));
        int sig = (rm > 0.f) ? (37 - ilogbf(rm)) : 0;
        ssig = sig;
        scale[row] = ldexp(1.0, -sig);
    }
    __syncthreads();
    const double s2 = ldexp(1.0, ssig);
    float xs[4] = {v.x, v.y, v.z, v.w};
    signed char out[5][4];
#pragma unroll
    for (int e = 0; e < 4; ++e) {
        long X = __double2ll_rn((double)xs[e] * s2);
#pragma unroll
        for (int l = 0; l < 4; ++l) {
            int d = (int)(((X + 128) & 255) - 128);
            out[l][e] = (signed char)d;
            X = (X - d) >> 8;
        }
        out[4][e] = (signed char)X;
    }
#pragma unroll
    for (int l = 0; l < 5; ++l)
        *(char4*)&limbs[(size_t)l * plane_stride + (size_t)row * 1024 + tid * 4] =
            *(char4*)&out[l][0];
}

// ---------- exact i8-MFMA projection, LDS-free: fragments straight from L2 ----------
// Same MFMA sequence and exact i32 accumulation as R5/R9 -> bit-identical output.
// No barriers: compiler free to pipeline loads across K-iterations.
__global__ __launch_bounds__(256) void gemm_i8qk(
    const signed char* __restrict__ Xl,
    const signed char* __restrict__ Wql,
    const signed char* __restrict__ Wkl,
    const double* __restrict__ xsc,
    const double* __restrict__ wqsc, const double* __restrict__ wksc,
    const float* __restrict__ bq, const float* __restrict__ bk,
    double* __restrict__ Qd, double* __restrict__ Kd)
{
    const int K = 1024, N = 1024;
    const long MK = 2048L * 1024, NK = 1024L * 1024;
    const signed char* Wl = blockIdx.z ? Wkl : Wql;
    const double* wsc = blockIdx.z ? wksc : wqsc;
    const float* bias = blockIdx.z ? bk : bq;
    double* C = blockIdx.z ? Kd : Qd;

    const int tid  = threadIdx.x;
    const int lane = tid & 63, wave = tid >> 6;
    const int wm = wave >> 1, wn = wave & 1;     // 2x2 waves, 32x32 out each
    const int quad = lane >> 4, l16 = lane & 15;
    const int m0 = blockIdx.y * 64, n0 = blockIdx.x * 64;

    // fragment source rows (identical byte->lane mapping as the LDS version)
    const signed char* a0p = Xl + (size_t)(m0 + wm * 32 +      l16) * K + quad * 16;
    const signed char* a1p = Xl + (size_t)(m0 + wm * 32 + 16 + l16) * K + quad * 16;
    const signed char* b0p = Wl + (size_t)(n0 + wn * 32 +      l16) * K + quad * 16;
    const signed char* b1p = Wl + (size_t)(n0 + wn * 32 + 16 + l16) * K + quad * 16;

    i4v acc[6][2][2] = {};

    for (int k0 = 0; k0 < K; k0 += 64) {
        i4v bF[5][2];
#pragma unroll
        for (int j = 0; j < 5; ++j) {
            bF[j][0] = *(const i4v*)(b0p + j * NK + k0);
            bF[j][1] = *(const i4v*)(b1p + j * NK + k0);
        }
#pragma unroll
        for (int i = 0; i < 5; ++i) {
            i4v a0 = *(const i4v*)(a0p + i * MK + k0);
            i4v a1 = *(const i4v*)(a1p + i * MK + k0);
#pragma unroll
            for (int j = 0; j < 5; ++j) {
                if (i + j < 3) continue;
                const int s = i + j - 3;
                acc[s][0][0] = __builtin_amdgcn_mfma_i32_16x16x64_i8(a0, bF[j][0], acc[s][0][0], 0, 0, 0);
                acc[s][0][1] = __builtin_amdgcn_mfma_i32_16x16x64_i8(a0, bF[j][1], acc[s][0][1], 0, 0, 0);
                acc[s][1][0] = __builtin_amdgcn_mfma_i32_16x16x64_i8(a1, bF[j][0], acc[s][1][0], 0, 0, 0);
                acc[s][1][1] = __builtin_amdgcn_mfma_i32_16x16x64_i8(a1, bF[j][1], acc[s][1][1], 0, 0, 0);
            }
        }
    }

    const double wt0 = ldexp(1.0, 24), wt1 = ldexp(1.0, 32), wt2 = ldexp(1.0, 40);
    const double wt3 = ldexp(1.0, 48), wt4 = ldexp(1.0, 56), wt5 = ldexp(1.0, 64);
#pragma unroll
    for (int mt = 0; mt < 2; ++mt)
#pragma unroll
        for (int nt = 0; nt < 2; ++nt)
#pragma unroll
            for (int r = 0; r < 4; ++r) {
                int row = m0 + wm * 32 + mt * 16 + quad * 4 + r;
                int col = n0 + wn * 32 + nt * 16 + l16;
                double dsum = wt0 * (double)acc[0][mt][nt][r]
                            + wt1 * (double)acc[1][mt][nt][r]
                            + wt2 * (double)acc[2][mt][nt][r]
                            + wt3 * (double)acc[3][mt][nt][r]
                            + wt4 * (double)acc[4][mt][nt][r]
                            + wt5 * (double)acc[5][mt][nt][r];
                C[(size_t)row * N + col] = dsum * xsc[row] * wsc[col] + (double)bias[col];
            }
}

// ------- V projection: 64x64 tile, split-bf16 (R9-proven) -------
__global__ __launch_bounds__(256) void gemm_v64(
    const float* __restrict__ A, const float* __restrict__ B,
    const float* __restrict__ bias, float* __restrict__ C)
{
    const int K = 1024, N = 1024;
    __shared__ short Ah[64][40];
    __shared__ short Al[64][40];
    __shared__ short Bh[64][40];
    __shared__ short Bl[64][40];

    const int tid = threadIdx.x, lane = tid & 63, wave = tid >> 6;
    const int wm = wave >> 1, wn = wave & 1;
    const int quad = lane >> 4, l16 = lane & 15;
    const int m0 = blockIdx.y * 64, n0 = blockIdx.x * 64;
    const int srow = tid >> 2, sco = (tid & 3) * 8;
    const float* ap = A + (size_t)(m0 + srow) * K + sco;
    const float* bp = B + (size_t)(n0 + srow) * K + sco;

    f4 acc[2][2] = {};
    for (int k0 = 0; k0 < K; k0 += 32) {
        float av[8], bv[8];
        *(float4*)&av[0] = *(const float4*)(ap + k0);
        *(float4*)&av[4] = *(const float4*)(ap + k0 + 4);
        *(float4*)&bv[0] = *(const float4*)(bp + k0);
        *(float4*)&bv[4] = *(const float4*)(bp + k0 + 4);
        __align__(16) short ahv[8], alv[8], bhv[8], blv[8];
#pragma unroll
        for (int i = 0; i < 8; ++i) {
            short h = f2bf(av[i]); ahv[i] = h; alv[i] = f2bf(av[i] - bf2f(h));
            short g = f2bf(bv[i]); bhv[i] = g; blv[i] = f2bf(bv[i] - bf2f(g));
        }
        __syncthreads();
        *(s8v*)&Ah[srow][sco] = *(s8v*)&ahv[0];
        *(s8v*)&Al[srow][sco] = *(s8v*)&alv[0];
        *(s8v*)&Bh[srow][sco] = *(s8v*)&bhv[0];
        *(s8v*)&Bl[srow][sco] = *(s8v*)&blv[0];
        __syncthreads();

        s8v af[2], afl[2], bf[2], bfl[2];
#pragma unroll
        for (int t = 0; t < 2; ++t) {
            af[t]  = *(s8v*)&Ah[wm * 32 + t * 16 + l16][quad * 8];
            afl[t] = *(s8v*)&Al[wm * 32 + t * 16 + l16][quad * 8];
            bf[t]  = *(s8v*)&Bh[wn * 32 + t * 16 + l16][quad * 8];
            bfl[t] = *(s8v*)&Bl[wn * 32 + t * 16 + l16][quad * 8];
        }
#pragma unroll
        for (int mt = 0; mt < 2; ++mt)
#pragma unroll
            for (int nt = 0; nt < 2; ++nt) {
                acc[mt][nt] = __builtin_amdgcn_mfma_f32_16x16x32_bf16(af[mt],  bf[nt],  acc[mt][nt], 0, 0, 0);
                acc[mt][nt] = __builtin_amdgcn_mfma_f32_16x16x32_bf16(af[mt],  bfl[nt], acc[mt][nt], 0, 0, 0);
                acc[mt][nt] = __builtin_amdgcn_mfma_f32_16x16x32_bf16(afl[mt], bf[nt],  acc[mt][nt], 0, 0, 0);
            }
    }
#pragma unroll
    for (int mt = 0; mt < 2; ++mt)
#pragma unroll
        for (int nt = 0; nt < 2; ++nt)
#pragma unroll
            for (int r = 0; r < 4; ++r) {
                int row = m0 + wm * 32 + mt * 16 + quad * 4 + r;
                int col = n0 + wn * 32 + nt * 16 + l16;
                C[(size_t)row * N + col] = acc[mt][nt][r] + bias[col];
            }
}

// ------- score GEMM: 64x64 tile, bf16 inputs, fp32 out (R8-proven) -------
__global__ __launch_bounds__(256) void gemm_score(
    const short* __restrict__ Qh, const short* __restrict__ Kh,
    float* __restrict__ C)
{
    const int K = 1024, N = 2048;
    __shared__ short As[64][40];
    __shared__ short Bs[64][40];
    const int tid = threadIdx.x, lane = tid & 63, wave = tid >> 6;
    const int wm = wave >> 1, wn = wave & 1;
    const int quad = lane >> 4, l16 = lane & 15;
    const int m0 = blockIdx.y * 64, n0 = blockIdx.x * 64;
    const int srow = tid >> 2, sco = (tid & 3) * 8;
    const short* ap = Qh + (size_t)(m0 + srow) * K + sco;
    const short* bp = Kh + (size_t)(n0 + srow) * K + sco;

    f4 acc[2][2] = {};
    for (int k0 = 0; k0 < K; k0 += 32) {
        s8v a8 = *(const s8v*)(ap + k0);
        s8v b8 = *(const s8v*)(bp + k0);
        __syncthreads();
        *(s8v*)&As[srow][sco] = a8;
        *(s8v*)&Bs[srow][sco] = b8;
        __syncthreads();
        s8v af[2], bf[2];
#pragma unroll
        for (int t = 0; t < 2; ++t) {
            af[t] = *(s8v*)&As[wm * 32 + t * 16 + l16][quad * 8];
            bf[t] = *(s8v*)&Bs[wn * 32 + t * 16 + l16][quad * 8];
        }
#pragma unroll
        for (int mt = 0; mt < 2; ++mt)
#pragma unroll
            for (int nt = 0; nt < 2; ++nt)
                acc[mt][nt] = __builtin_amdgcn_mfma_f32_16x16x32_bf16(
                    af[mt], bf[nt], acc[mt][nt], 0, 0, 0);
    }
#pragma unroll
    for (int mt = 0; mt < 2; ++mt)
#pragma unroll
        for (int nt = 0; nt < 2; ++nt)
#pragma unroll
            for (int r = 0; r < 4; ++r) {
                int row = m0 + wm * 32 + mt * 16 + quad * 4 + r;
                int col = n0 + wn * 32 + nt * 16 + l16;
                C[(size_t)row * N + col] = acc[mt][nt][r];
            }
}

// ------- fp64 L2 normalize rows (in place) + bf16 copy (R8-proven) -------
__global__ __launch_bounds__(256) void l2norm_f64bf16(
    double* __restrict__ d, short* __restrict__ h)
{
    const int row = blockIdx.x;
    const int tid = threadIdx.x;
    double* p = d + (size_t)row * 1024 + tid * 4;
    double v0 = p[0], v1 = p[1], v2 = p[2], v3 = p[3];
    double s = v0 * v0 + v1 * v1 + v2 * v2 + v3 * v3;
#pragma unroll
    for (int off = 32; off > 0; off >>= 1) s += __shfl_down(s, off);
    __shared__ double ws[5];
    if ((tid & 63) == 0) ws[tid >> 6] = s;
    __syncthreads();
    if (tid == 0) ws[4] = fmax(sqrt(ws[0] + ws[1] + ws[2] + ws[3]), 1e-12);
    __syncthreads();
    double n = ws[4];
    double o0 = v0 / n, o1 = v1 / n, o2 = v2 / n, o3 = v3 / n;
    p[0] = o0; p[1] = o1; p[2] = o2; p[3] = o3;
    __align__(8) short hv[4] = {f2bf((float)o0), f2bf((float)o1),
                                f2bf((float)o2), f2bf((float)o3)};
    *(short4*)&h[(size_t)row * 1024 + tid * 4] = *(short4*)hv;
}

// ------- top-16 via shuffle-argmax + fp64 rerank + route (R9-proven) -------
__global__ __launch_bounds__(256) void topk_route(
    const float*  __restrict__ S,
    const double* __restrict__ Qd,
    const double* __restrict__ Kd,
    const float*  __restrict__ Vf,
    float* __restrict__ routes_out,
    float* __restrict__ weights_out,
    float* __restrict__ feat_out,
    int batch)
{
    const int P = 2048, D = 1024;
    __shared__ float  sc[2048];
    __shared__ double qrow[1024];
    __shared__ float  wval[4];
    __shared__ int    widx[4];
    __shared__ int    cidx[16];
    __shared__ double cscore[16];
    __shared__ int    topi_s[8];
    __shared__ float  wts[8];

    const int p = blockIdx.x;
    const int tid = threadIdx.x;
    const int lane = tid & 63, wave = tid >> 6;

    const float4* sr4 = (const float4*)(S + (size_t)p * P);
    ((float4*)sc)[tid]       = sr4[tid];
    ((float4*)sc)[tid + 256] = sr4[tid + 256];
    {
        const double* q = Qd + (size_t)p * D + tid * 4;
        qrow[tid * 4 + 0] = q[0]; qrow[tid * 4 + 1] = q[1];
        qrow[tid * 4 + 2] = q[2]; qrow[tid * 4 + 3] = q[3];
    }
    __syncthreads();
    if (tid == 0) sc[p] = -1e30f;
    __syncthreads();

    for (int it = 0; it < 16; ++it) {
        float bv = -INFINITY; int bi = 0x7fffffff;
#pragma unroll
        for (int r = 0; r < 8; ++r) {
            int j = tid + r * 256;
            float v = sc[j];
            if (v > bv || (v == bv && j < bi)) { bv = v; bi = j; }
        }
#pragma unroll
        for (int off = 32; off > 0; off >>= 1) {
            float ov = __shfl_down(bv, off);
            int   oi = __shfl_down(bi, off);
            if (ov > bv || (ov == bv && oi < bi)) { bv = ov; bi = oi; }
        }
        if (lane == 0) { wval[wave] = bv; widx[wave] = bi; }
        __syncthreads();
        if (tid == 0) {
            float gv = wval[0]; int gi = widx[0];
#pragma unroll
            for (int w = 1; w < 4; ++w) {
                if (wval[w] > gv || (wval[w] == gv && widx[w] < gi)) {
                    gv = wval[w]; gi = widx[w];
                }
            }
            cidx[it] = gi;
            sc[gi] = -INFINITY;
        }
        __syncthreads();
    }

    {
        const int cand = tid >> 4;
        const int l = tid & 15;
        const double* krow = Kd + (size_t)cidx[cand] * D;
        double s = 0.0;
#pragma unroll 8
        for (int j = 0; j < 64; ++j) {
            int e = l + j * 16;
            s = fma(qrow[e], krow[e], s);
        }
        s += __shfl_down(s, 8);
        s += __shfl_down(s, 4);
        s += __shfl_down(s, 2);
        s += __shfl_down(s, 1);
        if (l == 0) cscore[cand] = s;
    }
    __syncthreads();

    if (tid == 0) {
        unsigned used = 0;
        double tv[8]; int ti[8];
        for (int k = 0; k < 8; ++k) {
            int best = -1;
            for (int c = 0; c < 16; ++c) {
                if (used & (1u << c)) continue;
                if (best < 0 || cscore[c] > cscore[best] ||
                    (cscore[c] == cscore[best] && cidx[c] < cidx[best])) best = c;
            }
            used |= 1u << best;
            tv[k] = cscore[best]; ti[k] = cidx[best];
        }
        double m = tv[0], e[8], sum = 0.0;
        for (int k = 0; k < 8; ++k) { e[k] = exp((tv[k] - m) / TEMP); sum += e[k]; }
        const size_t row = (size_t)batch * P + p;
        for (int k = 0; k < 8; ++k) {
            float wk = (float)(e[k] / sum);
            wts[k] = wk; topi_s[k] = ti[k];
            routes_out[row * 8 + k]  = (float)ti[k];
            weights_out[row * 8 + k] = wk;
        }
    }
    __syncthreads();

    float4 a = {0.f, 0.f, 0.f, 0.f};
#pragma unroll
    for (int k = 0; k < 8; ++k) {
        const float4 v4 = ((const float4*)(Vf + (size_t)topi_s[k] * D))[tid];
        float wk = wts[k];
        a.x = fmaf(wk, v4.x, a.x);
        a.y = fmaf(wk, v4.y, a.y);
        a.z = fmaf(wk, v4.z, a.z);
        a.w = fmaf(wk, v4.w, a.w);
    }
    ((float4*)(feat_out + ((size_t)batch * P + p) * D))[tid] = a;
}

extern "C" void kernel_launch(void* const* d_in, const int* in_sizes, int n_in,
                              void* d_out, int out_size, void* d_ws, size_t ws_size,
                              hipStream_t stream)
{
    const float* x  = (const float*)d_in[0];  // (4,2049,1024)
    const float* Wq = (const float*)d_in[1];
    const float* bq = (const float*)d_in[2];
    const float* Wk = (const float*)d_in[3];
    const float* bk = (const float*)d_in[4];
    const float* Wv = (const float*)d_in[5];
    const float* bv = (const float*)d_in[6];

    const int B = 4, P = 2048, D = 1024;
    const size_t PD = (size_t)P * D;

    double* Qd   = (double*)d_ws;             // P*D f64
    double* Kd   = Qd + PD;
    double* xsc  = Kd + PD;                   // 2048
    double* wqsc = xsc + 2048;                // 1024
    double* wksc = wqsc + 1024;               // 1024
    short*  Qh   = (short*)(wksc + 1024);     // P*D bf16
    short*  Kh   = Qh + PD;
    float*  Vf   = (float*)(Kh + PD);         // P*D f32
    float*  Sf   = Vf + PD;                   // P*P f32
    signed char* Xl  = (signed char*)(Sf + (size_t)P * P);  // 5*P*D
    signed char* Wql = Xl + 5 * PD;                          // 5*D*D
    signed char* Wkl = Wql + 5 * (size_t)D * D;

    float* out     = (float*)d_out;
    float* routes  = out;
    float* weights = out + (size_t)B * P * 8;
    float* feat    = out + (size_t)B * P * 16;

    dim3 blk(256);
    quantize_rows<<<dim3(1024), blk, 0, stream>>>(Wq, Wql, (long)D * D, wqsc);
    quantize_rows<<<dim3(1024), blk, 0, stream>>>(Wk, Wkl, (long)D * D, wksc);

    for (int b = 0; b < B; ++b) {
        const float* xb = x + ((size_t)b * 2049 + 1) * D;  // rows 1..2048 contiguous
        quantize_rows<<<dim3(P), blk, 0, stream>>>(xb, Xl, (long)P * D, xsc);
        gemm_i8qk<<<dim3(16, 32, 2), blk, 0, stream>>>(Xl, Wql, Wkl, xsc, wqsc, wksc,
                                                       bq, bk, Qd, Kd);
        gemm_v64<<<dim3(16, 32), blk, 0, stream>>>(xb, Wv, bv, Vf);
        l2norm_f64bf16<<<dim3(P), blk, 0, stream>>>(Qd, Qh);
        l2norm_f64bf16<<<dim3(P), blk, 0, stream>>>(Kd, Kh);
        gemm_score<<<dim3(32, 32), blk, 0, stream>>>(Qh, Kh, Sf);
        topk_route<<<dim3(P), blk, 0, stream>>>(Sf, Qd, Kd, Vf, routes, weights, feat, b);
    }
}

// Round 12
// 1099.368 us; speedup vs baseline: 1.2588x; 1.2588x over previous
//
#include <hip/hip_runtime.h>
#include <hip/hip_bf16.h>
#include <math.h>

#define TEMP 0.1

typedef float f4 __attribute__((ext_vector_type(4)));
typedef short s8v __attribute__((ext_vector_type(8)));
typedef int   i4v __attribute__((ext_vector_type(4)));

__device__ inline short f2bf(float f) {
    __hip_bfloat16 h = __float2bfloat16(f);
    return *reinterpret_cast<short*>(&h);
}
__device__ inline float bf2f(short s) {
    __hip_bfloat16 h = *reinterpret_cast<__hip_bfloat16*>(&s);
    return __bfloat162float(h);
}

// ---------- quantize rows of length 1024 to 5 balanced int8 limbs (R5-proven) ----------
__global__ __launch_bounds__(256) void quantize_rows(
    const float* __restrict__ src, signed char* __restrict__ limbs,
    long plane_stride, double* __restrict__ scale)
{
    const int row = blockIdx.x, tid = threadIdx.x;
    const float4 v = ((const float4*)(src + (size_t)row * 1024))[tid];
    float m = fmaxf(fmaxf(fabsf(v.x), fabsf(v.y)), fmaxf(fabsf(v.z), fabsf(v.w)));
#pragma unroll
    for (int off = 32; off > 0; off >>= 1) m = fmaxf(m, __shfl_down(m, off));
    __shared__ float wmax[4];
    __shared__ int ssig;
    if ((tid & 63) == 0) wmax[tid >> 6] = m;
    __syncthreads();
    if (tid == 0) {
        float rm = fmaxf(fmaxf(wmax[0], wmax[1]), fmaxf(wmax[2], wmax[3]));
        int sig = (rm > 0.f) ? (37 - ilogbf(rm)) : 0;
        ssig = sig;
        scale[row] = ldexp(1.0, -sig);
    }
    __syncthreads();
    const double s2 = ldexp(1.0, ssig);
    float xs[4] = {v.x, v.y, v.z, v.w};
    signed char out[5][4];
#pragma unroll
    for (int e = 0; e < 4; ++e) {
        long X = __double2ll_rn((double)xs[e] * s2);
#pragma unroll
        for (int l = 0; l < 4; ++l) {
            int d = (int)(((X + 128) & 255) - 128);
            out[l][e] = (signed char)d;
            X = (X - d) >> 8;
        }
        out[4][e] = (signed char)X;
    }
#pragma unroll
    for (int l = 0; l < 5; ++l)
        *(char4*)&limbs[(size_t)l * plane_stride + (size_t)row * 1024 + tid * 4] =
            *(char4*)&out[l][0];
}

// ---------- exact i8-MFMA projection (R9-proven: LDS staging + reg prefetch) ----------
__global__ __launch_bounds__(256) void gemm_i8qk(
    const signed char* __restrict__ Xl,
    const signed char* __restrict__ Wql,
    const signed char* __restrict__ Wkl,
    const double* __restrict__ xsc,
    const double* __restrict__ wqsc, const double* __restrict__ wksc,
    const float* __restrict__ bq, const float* __restrict__ bk,
    double* __restrict__ Qd, double* __restrict__ Kd)
{
    const int K = 1024, N = 1024;
    const long MK = 2048L * 1024, NK = 1024L * 1024;
    const signed char* Wl = blockIdx.z ? Wkl : Wql;
    const double* wsc = blockIdx.z ? wksc : wqsc;
    const float* bias = blockIdx.z ? bk : bq;
    double* C = blockIdx.z ? Kd : Qd;

    __shared__ __align__(16) signed char Asm[5][64][80];
    __shared__ __align__(16) signed char Bsm[5][64][80];

    const int tid  = threadIdx.x;
    const int lane = tid & 63, wave = tid >> 6;
    const int wm = wave >> 1, wn = wave & 1;
    const int quad = lane >> 4, l16 = lane & 15;
    const int m0 = blockIdx.y * 64, n0 = blockIdx.x * 64;

    const int srow = tid >> 2, skq = (tid & 3) * 16;
    const signed char* ap = Xl + (size_t)(m0 + srow) * K + skq;
    const signed char* bp = Wl + (size_t)(n0 + srow) * K + skq;

    i4v acc[6][2][2] = {};

    i4v at[5], bt[5];
#pragma unroll
    for (int l = 0; l < 5; ++l) {
        at[l] = *(const i4v*)(ap + l * MK);
        bt[l] = *(const i4v*)(bp + l * NK);
    }

    for (int k0 = 0; k0 < K; k0 += 64) {
        __syncthreads();
#pragma unroll
        for (int l = 0; l < 5; ++l) {
            *(i4v*)&Asm[l][srow][skq] = at[l];
            *(i4v*)&Bsm[l][srow][skq] = bt[l];
        }
        __syncthreads();

        if (k0 + 64 < K) {
#pragma unroll
            for (int l = 0; l < 5; ++l) {
                at[l] = *(const i4v*)(ap + l * MK + k0 + 64);
                bt[l] = *(const i4v*)(bp + l * NK + k0 + 64);
            }
        }

        i4v bF[5][2];
#pragma unroll
        for (int j = 0; j < 5; ++j)
#pragma unroll
            for (int nt = 0; nt < 2; ++nt)
                bF[j][nt] = *(const i4v*)&Bsm[j][wn * 32 + nt * 16 + l16][quad * 16];

#pragma unroll
        for (int i = 0; i < 5; ++i) {
            i4v a0 = *(const i4v*)&Asm[i][wm * 32 +      l16][quad * 16];
            i4v a1 = *(const i4v*)&Asm[i][wm * 32 + 16 + l16][quad * 16];
#pragma unroll
            for (int j = 0; j < 5; ++j) {
                if (i + j < 3) continue;
                const int s = i + j - 3;
                acc[s][0][0] = __builtin_amdgcn_mfma_i32_16x16x64_i8(a0, bF[j][0], acc[s][0][0], 0, 0, 0);
                acc[s][0][1] = __builtin_amdgcn_mfma_i32_16x16x64_i8(a0, bF[j][1], acc[s][0][1], 0, 0, 0);
                acc[s][1][0] = __builtin_amdgcn_mfma_i32_16x16x64_i8(a1, bF[j][0], acc[s][1][0], 0, 0, 0);
                acc[s][1][1] = __builtin_amdgcn_mfma_i32_16x16x64_i8(a1, bF[j][1], acc[s][1][1], 0, 0, 0);
            }
        }
    }

    const double wt0 = ldexp(1.0, 24), wt1 = ldexp(1.0, 32), wt2 = ldexp(1.0, 40);
    const double wt3 = ldexp(1.0, 48), wt4 = ldexp(1.0, 56), wt5 = ldexp(1.0, 64);
#pragma unroll
    for (int mt = 0; mt < 2; ++mt)
#pragma unroll
        for (int nt = 0; nt < 2; ++nt)
#pragma unroll
            for (int r = 0; r < 4; ++r) {
                int row = m0 + wm * 32 + mt * 16 + quad * 4 + r;
                int col = n0 + wn * 32 + nt * 16 + l16;
                double dsum = wt0 * (double)acc[0][mt][nt][r]
                            + wt1 * (double)acc[1][mt][nt][r]
                            + wt2 * (double)acc[2][mt][nt][r]
                            + wt3 * (double)acc[3][mt][nt][r]
                            + wt4 * (double)acc[4][mt][nt][r]
                            + wt5 * (double)acc[5][mt][nt][r];
                C[(size_t)row * N + col] = dsum * xsc[row] * wsc[col] + (double)bias[col];
            }
}

// ------- V projection: 64x64 tile, split-bf16 (R9-proven) -------
__global__ __launch_bounds__(256) void gemm_v64(
    const float* __restrict__ A, const float* __restrict__ B,
    const float* __restrict__ bias, float* __restrict__ C)
{
    const int K = 1024, N = 1024;
    __shared__ short Ah[64][40];
    __shared__ short Al[64][40];
    __shared__ short Bh[64][40];
    __shared__ short Bl[64][40];

    const int tid = threadIdx.x, lane = tid & 63, wave = tid >> 6;
    const int wm = wave >> 1, wn = wave & 1;
    const int quad = lane >> 4, l16 = lane & 15;
    const int m0 = blockIdx.y * 64, n0 = blockIdx.x * 64;
    const int srow = tid >> 2, sco = (tid & 3) * 8;
    const float* ap = A + (size_t)(m0 + srow) * K + sco;
    const float* bp = B + (size_t)(n0 + srow) * K + sco;

    f4 acc[2][2] = {};
    for (int k0 = 0; k0 < K; k0 += 32) {
        float av[8], bv[8];
        *(float4*)&av[0] = *(const float4*)(ap + k0);
        *(float4*)&av[4] = *(const float4*)(ap + k0 + 4);
        *(float4*)&bv[0] = *(const float4*)(bp + k0);
        *(float4*)&bv[4] = *(const float4*)(bp + k0 + 4);
        __align__(16) short ahv[8], alv[8], bhv[8], blv[8];
#pragma unroll
        for (int i = 0; i < 8; ++i) {
            short h = f2bf(av[i]); ahv[i] = h; alv[i] = f2bf(av[i] - bf2f(h));
            short g = f2bf(bv[i]); bhv[i] = g; blv[i] = f2bf(bv[i] - bf2f(g));
        }
        __syncthreads();
        *(s8v*)&Ah[srow][sco] = *(s8v*)&ahv[0];
        *(s8v*)&Al[srow][sco] = *(s8v*)&alv[0];
        *(s8v*)&Bh[srow][sco] = *(s8v*)&bhv[0];
        *(s8v*)&Bl[srow][sco] = *(s8v*)&blv[0];
        __syncthreads();

        s8v af[2], afl[2], bf[2], bfl[2];
#pragma unroll
        for (int t = 0; t < 2; ++t) {
            af[t]  = *(s8v*)&Ah[wm * 32 + t * 16 + l16][quad * 8];
            afl[t] = *(s8v*)&Al[wm * 32 + t * 16 + l16][quad * 8];
            bf[t]  = *(s8v*)&Bh[wn * 32 + t * 16 + l16][quad * 8];
            bfl[t] = *(s8v*)&Bl[wn * 32 + t * 16 + l16][quad * 8];
        }
#pragma unroll
        for (int mt = 0; mt < 2; ++mt)
#pragma unroll
            for (int nt = 0; nt < 2; ++nt) {
                acc[mt][nt] = __builtin_amdgcn_mfma_f32_16x16x32_bf16(af[mt],  bf[nt],  acc[mt][nt], 0, 0, 0);
                acc[mt][nt] = __builtin_amdgcn_mfma_f32_16x16x32_bf16(af[mt],  bfl[nt], acc[mt][nt], 0, 0, 0);
                acc[mt][nt] = __builtin_amdgcn_mfma_f32_16x16x32_bf16(afl[mt], bf[nt],  acc[mt][nt], 0, 0, 0);
            }
    }
#pragma unroll
    for (int mt = 0; mt < 2; ++mt)
#pragma unroll
        for (int nt = 0; nt < 2; ++nt)
#pragma unroll
            for (int r = 0; r < 4; ++r) {
                int row = m0 + wm * 32 + mt * 16 + quad * 4 + r;
                int col = n0 + wn * 32 + nt * 16 + l16;
                C[(size_t)row * N + col] = acc[mt][nt][r] + bias[col];
            }
}

// ------- score GEMM: 64x64 tile, bf16 inputs, fp32 out (R8-proven) -------
__global__ __launch_bounds__(256) void gemm_score(
    const short* __restrict__ Qh, const short* __restrict__ Kh,
    float* __restrict__ C)
{
    const int K = 1024, N = 2048;
    __shared__ short As[64][40];
    __shared__ short Bs[64][40];
    const int tid = threadIdx.x, lane = tid & 63, wave = tid >> 6;
    const int wm = wave >> 1, wn = wave & 1;
    const int quad = lane >> 4, l16 = lane & 15;
    const int m0 = blockIdx.y * 64, n0 = blockIdx.x * 64;
    const int srow = tid >> 2, sco = (tid & 3) * 8;
    const short* ap = Qh + (size_t)(m0 + srow) * K + sco;
    const short* bp = Kh + (size_t)(n0 + srow) * K + sco;

    f4 acc[2][2] = {};
    for (int k0 = 0; k0 < K; k0 += 32) {
        s8v a8 = *(const s8v*)(ap + k0);
        s8v b8 = *(const s8v*)(bp + k0);
        __syncthreads();
        *(s8v*)&As[srow][sco] = a8;
        *(s8v*)&Bs[srow][sco] = b8;
        __syncthreads();
        s8v af[2], bf[2];
#pragma unroll
        for (int t = 0; t < 2; ++t) {
            af[t] = *(s8v*)&As[wm * 32 + t * 16 + l16][quad * 8];
            bf[t] = *(s8v*)&Bs[wn * 32 + t * 16 + l16][quad * 8];
        }
#pragma unroll
        for (int mt = 0; mt < 2; ++mt)
#pragma unroll
            for (int nt = 0; nt < 2; ++nt)
                acc[mt][nt] = __builtin_amdgcn_mfma_f32_16x16x32_bf16(
                    af[mt], bf[nt], acc[mt][nt], 0, 0, 0);
    }
#pragma unroll
    for (int mt = 0; mt < 2; ++mt)
#pragma unroll
        for (int nt = 0; nt < 2; ++nt)
#pragma unroll
            for (int r = 0; r < 4; ++r) {
                int row = m0 + wm * 32 + mt * 16 + quad * 4 + r;
                int col = n0 + wn * 32 + nt * 16 + l16;
                C[(size_t)row * N + col] = acc[mt][nt][r];
            }
}

// ------- fp64 L2 normalize + bf16 copy; z selects Q or K (fused dispatch) -------
__global__ __launch_bounds__(256) void l2norm_f64bf16(
    double* __restrict__ dq, double* __restrict__ dk,
    short* __restrict__ hq, short* __restrict__ hk)
{
    double* d = blockIdx.y ? dk : dq;
    short*  h = blockIdx.y ? hk : hq;
    const int row = blockIdx.x;
    const int tid = threadIdx.x;
    double* p = d + (size_t)row * 1024 + tid * 4;
    double v0 = p[0], v1 = p[1], v2 = p[2], v3 = p[3];
    double s = v0 * v0 + v1 * v1 + v2 * v2 + v3 * v3;
#pragma unroll
    for (int off = 32; off > 0; off >>= 1) s += __shfl_down(s, off);
    __shared__ double ws[5];
    if ((tid & 63) == 0) ws[tid >> 6] = s;
    __syncthreads();
    if (tid == 0) ws[4] = fmax(sqrt(ws[0] + ws[1] + ws[2] + ws[3]), 1e-12);
    __syncthreads();
    double n = ws[4];
    double o0 = v0 / n, o1 = v1 / n, o2 = v2 / n, o3 = v3 / n;
    p[0] = o0; p[1] = o1; p[2] = o2; p[3] = o3;
    __align__(8) short hv[4] = {f2bf((float)o0), f2bf((float)o1),
                                f2bf((float)o2), f2bf((float)o3)};
    *(short4*)&h[(size_t)row * 1024 + tid * 4] = *(short4*)hv;
}

// ------- top-16 via tournament argmax (identical semantics) + fp64 rerank + route -------
__global__ __launch_bounds__(256) void topk_route(
    const float*  __restrict__ S,
    const double* __restrict__ Qd,
    const double* __restrict__ Kd,
    const float*  __restrict__ Vf,
    float* __restrict__ routes_out,
    float* __restrict__ weights_out,
    float* __restrict__ feat_out,
    int batch)
{
    const int P = 2048, D = 1024;
    __shared__ float  sc[2048];
    __shared__ double qrow[1024];
    __shared__ float  wval[4];
    __shared__ int    widx[4];
    __shared__ int    gi_s;
    __shared__ int    cidx[16];
    __shared__ double cscore[16];
    __shared__ int    topi_s[8];
    __shared__ float  wts[8];

    const int p = blockIdx.x;
    const int tid = threadIdx.x;
    const int lane = tid & 63, wave = tid >> 6;

    const float4* sr4 = (const float4*)(S + (size_t)p * P);
    ((float4*)sc)[tid]       = sr4[tid];
    ((float4*)sc)[tid + 256] = sr4[tid + 256];
    {
        const double* q = Qd + (size_t)p * D + tid * 4;
        qrow[tid * 4 + 0] = q[0]; qrow[tid * 4 + 1] = q[1];
        qrow[tid * 4 + 2] = q[2]; qrow[tid * 4 + 3] = q[3];
    }
    __syncthreads();
    if (tid == 0) sc[p] = -1e30f;
    __syncthreads();

    // local best over this thread's 8 strided elements (registers)
    float lv = -INFINITY; int li = 0x7fffffff;
#pragma unroll
    for (int r = 0; r < 8; ++r) {
        int j = tid + r * 256;
        float v = sc[j];
        if (v > lv || (v == lv && j < li)) { lv = v; li = j; }
    }

    for (int it = 0; it < 16; ++it) {
        float bv = lv; int bi = li;
#pragma unroll
        for (int off = 32; off > 0; off >>= 1) {
            float ov = __shfl_down(bv, off);
            int   oi = __shfl_down(bi, off);
            if (ov > bv || (ov == bv && oi < bi)) { bv = ov; bi = oi; }
        }
        if (lane == 0) { wval[wave] = bv; widx[wave] = bi; }
        __syncthreads();
        if (tid == 0) {
            float gv = wval[0]; int gi = widx[0];
#pragma unroll
            for (int w = 1; w < 4; ++w) {
                if (wval[w] > gv || (wval[w] == gv && widx[w] < gi)) {
                    gv = wval[w]; gi = widx[w];
                }
            }
            cidx[it] = gi; gi_s = gi;
            sc[gi] = -INFINITY;
        }
        __syncthreads();
        // only the winner's owner rescans its 8 elements
        if ((gi_s & 255) == tid) {
            lv = -INFINITY; li = 0x7fffffff;
#pragma unroll
            for (int r = 0; r < 8; ++r) {
                int j = tid + r * 256;
                float v = sc[j];
                if (v > lv || (v == lv && j < li)) { lv = v; li = j; }
            }
        }
    }

    {
        const int cand = tid >> 4;
        const int l = tid & 15;
        const double* krow = Kd + (size_t)cidx[cand] * D;
        double s = 0.0;
#pragma unroll 8
        for (int j = 0; j < 64; ++j) {
            int e = l + j * 16;
            s = fma(qrow[e], krow[e], s);
        }
        s += __shfl_down(s, 8);
        s += __shfl_down(s, 4);
        s += __shfl_down(s, 2);
        s += __shfl_down(s, 1);
        if (l == 0) cscore[cand] = s;
    }
    __syncthreads();

    if (tid == 0) {
        unsigned used = 0;
        double tv[8]; int ti[8];
        for (int k = 0; k < 8; ++k) {
            int best = -1;
            for (int c = 0; c < 16; ++c) {
                if (used & (1u << c)) continue;
                if (best < 0 || cscore[c] > cscore[best] ||
                    (cscore[c] == cscore[best] && cidx[c] < cidx[best])) best = c;
            }
            used |= 1u << best;
            tv[k] = cscore[best]; ti[k] = cidx[best];
        }
        double m = tv[0], e[8], sum = 0.0;
        for (int k = 0; k < 8; ++k) { e[k] = exp((tv[k] - m) / TEMP); sum += e[k]; }
        const size_t row = (size_t)batch * P + p;
        for (int k = 0; k < 8; ++k) {
            float wk = (float)(e[k] / sum);
            wts[k] = wk; topi_s[k] = ti[k];
            routes_out[row * 8 + k]  = (float)ti[k];
            weights_out[row * 8 + k] = wk;
        }
    }
    __syncthreads();

    float4 a = {0.f, 0.f, 0.f, 0.f};
#pragma unroll
    for (int k = 0; k < 8; ++k) {
        const float4 v4 = ((const float4*)(Vf + (size_t)topi_s[k] * D))[tid];
        float wk = wts[k];
        a.x = fmaf(wk, v4.x, a.x);
        a.y = fmaf(wk, v4.y, a.y);
        a.z = fmaf(wk, v4.z, a.z);
        a.w = fmaf(wk, v4.w, a.w);
    }
    ((float4*)(feat_out + ((size_t)batch * P + p) * D))[tid] = a;
}

extern "C" void kernel_launch(void* const* d_in, const int* in_sizes, int n_in,
                              void* d_out, int out_size, void* d_ws, size_t ws_size,
                              hipStream_t stream)
{
    const float* x  = (const float*)d_in[0];  // (4,2049,1024)
    const float* Wq = (const float*)d_in[1];
    const float* bq = (const float*)d_in[2];
    const float* Wk = (const float*)d_in[3];
    const float* bk = (const float*)d_in[4];
    const float* Wv = (const float*)d_in[5];
    const float* bv = (const float*)d_in[6];

    const int B = 4, P = 2048, D = 1024;
    const size_t PD = (size_t)P * D;

    double* Qd   = (double*)d_ws;             // P*D f64
    double* Kd   = Qd + PD;
    double* xsc  = Kd + PD;                   // 2048
    double* wqsc = xsc + 2048;                // 1024
    double* wksc = wqsc + 1024;               // 1024
    short*  Qh   = (short*)(wksc + 1024);     // P*D bf16
    short*  Kh   = Qh + PD;
    float*  Vf   = (float*)(Kh + PD);         // P*D f32
    float*  Sf   = Vf + PD;                   // P*P f32
    signed char* Xl  = (signed char*)(Sf + (size_t)P * P);  // 5*P*D
    signed char* Wql = Xl + 5 * PD;                          // 5*D*D
    signed char* Wkl = Wql + 5 * (size_t)D * D;

    float* out     = (float*)d_out;
    float* routes  = out;
    float* weights = out + (size_t)B * P * 8;
    float* feat    = out + (size_t)B * P * 16;

    dim3 blk(256);
    quantize_rows<<<dim3(1024), blk, 0, stream>>>(Wq, Wql, (long)D * D, wqsc);
    quantize_rows<<<dim3(1024), blk, 0, stream>>>(Wk, Wkl, (long)D * D, wksc);

    for (int b = 0; b < B; ++b) {
        const float* xb = x + ((size_t)b * 2049 + 1) * D;  // rows 1..2048 contiguous
        quantize_rows<<<dim3(P), blk, 0, stream>>>(xb, Xl, (long)P * D, xsc);
        gemm_i8qk<<<dim3(16, 32, 2), blk, 0, stream>>>(Xl, Wql, Wkl, xsc, wqsc, wksc,
                                                       bq, bk, Qd, Kd);
        gemm_v64<<<dim3(16, 32), blk, 0, stream>>>(xb, Wv, bv, Vf);
        l2norm_f64bf16<<<dim3(P, 2), blk, 0, stream>>>(Qd, Kd, Qh, Kh);
        gemm_score<<<dim3(32, 32), blk, 0, stream>>>(Qh, Kh, Sf);
        topk_route<<<dim3(P), blk, 0, stream>>>(Sf, Qd, Kd, Vf, routes, weights, feat, b);
    }
}

// Round 13
// 952.266 us; speedup vs baseline: 1.4533x; 1.1545x over previous
//
#include <hip/hip_runtime.h>
#include <hip/hip_bf16.h>
#include <math.h>

#define TEMP 0.1

typedef float f4 __attribute__((ext_vector_type(4)));
typedef short s8v __attribute__((ext_vector_type(8)));
typedef int   i4v __attribute__((ext_vector_type(4)));

__device__ inline short f2bf(float f) {
    __hip_bfloat16 h = __float2bfloat16(f);
    return *reinterpret_cast<short*>(&h);
}
__device__ inline float bf2f(short s) {
    __hip_bfloat16 h = *reinterpret_cast<__hip_bfloat16*>(&s);
    return __bfloat162float(h);
}

// ---------- quantize rows of 1024 to 4 balanced int8 limbs (R6 code; numerics re-tested) ----------
// X = round(x * 2^sig), sig = 29 - ilogb(rowmax) => |X| < 2^30, top limb |d3| <= 64.
__global__ __launch_bounds__(256) void quantize_rows(
    const float* __restrict__ src, signed char* __restrict__ limbs,
    long plane_stride, double* __restrict__ scale)
{
    const int row = blockIdx.x, tid = threadIdx.x;
    const float4 v = ((const float4*)(src + (size_t)row * 1024))[tid];
    float m = fmaxf(fmaxf(fabsf(v.x), fabsf(v.y)), fmaxf(fabsf(v.z), fabsf(v.w)));
#pragma unroll
    for (int off = 32; off > 0; off >>= 1) m = fmaxf(m, __shfl_down(m, off));
    __shared__ float wmax[4];
    __shared__ int ssig;
    if ((tid & 63) == 0) wmax[tid >> 6] = m;
    __syncthreads();
    if (tid == 0) {
        float rm = fmaxf(fmaxf(wmax[0], wmax[1]), fmaxf(wmax[2], wmax[3]));
        int sig = (rm > 0.f) ? (29 - ilogbf(rm)) : 0;
        ssig = sig;
        scale[row] = ldexp(1.0, -sig);
    }
    __syncthreads();
    const double s2 = ldexp(1.0, ssig);
    float xs[4] = {v.x, v.y, v.z, v.w};
    signed char out[4][4];
#pragma unroll
    for (int e = 0; e < 4; ++e) {
        long X = __double2ll_rn((double)xs[e] * s2);
#pragma unroll
        for (int l = 0; l < 3; ++l) {
            int d = (int)(((X + 128) & 255) - 128);
            out[l][e] = (signed char)d;
            X = (X - d) >> 8;
        }
        out[3][e] = (signed char)X;
    }
#pragma unroll
    for (int l = 0; l < 4; ++l)
        *(char4*)&limbs[(size_t)l * plane_stride + (size_t)row * 1024 + tid * 4] =
            *(char4*)&out[l][0];
}

// ---------- fp32 -> bf16 hi/lo split planes (exactly the f2bf chain gemm_v64 used) ----------
__global__ __launch_bounds__(256) void tobf16_split(
    const float* __restrict__ src, short* __restrict__ hi, short* __restrict__ lo)
{
    const int row = blockIdx.x, tid = threadIdx.x;
    const float4 v = ((const float4*)(src + (size_t)row * 1024))[tid];
    float xs[4] = {v.x, v.y, v.z, v.w};
    __align__(8) short h[4], l[4];
#pragma unroll
    for (int e = 0; e < 4; ++e) {
        h[e] = f2bf(xs[e]);
        l[e] = f2bf(xs[e] - bf2f(h[e]));
    }
    *(short4*)&hi[(size_t)row * 1024 + tid * 4] = *(short4*)h;
    *(short4*)&lo[(size_t)row * 1024 + tid * 4] = *(short4*)l;
}

// ---------- exact i8-MFMA projection: 4 limb planes, 13 pairs (i+j>=2), 5 levels ----------
// LDS staging + register prefetch (R9-proven structure).
__global__ __launch_bounds__(256) void gemm_i8qk(
    const signed char* __restrict__ Xl,
    const signed char* __restrict__ Wql,
    const signed char* __restrict__ Wkl,
    const double* __restrict__ xsc,
    const double* __restrict__ wqsc, const double* __restrict__ wksc,
    const float* __restrict__ bq, const float* __restrict__ bk,
    double* __restrict__ Qd, double* __restrict__ Kd)
{
    const int K = 1024, N = 1024;
    const long MK = 2048L * 1024, NK = 1024L * 1024;
    const signed char* Wl = blockIdx.z ? Wkl : Wql;
    const double* wsc = blockIdx.z ? wksc : wqsc;
    const float* bias = blockIdx.z ? bk : bq;
    double* C = blockIdx.z ? Kd : Qd;

    __shared__ __align__(16) signed char Asm[4][64][80];
    __shared__ __align__(16) signed char Bsm[4][64][80];

    const int tid  = threadIdx.x;
    const int lane = tid & 63, wave = tid >> 6;
    const int wm = wave >> 1, wn = wave & 1;
    const int quad = lane >> 4, l16 = lane & 15;
    const int m0 = blockIdx.y * 64, n0 = blockIdx.x * 64;

    const int srow = tid >> 2, skq = (tid & 3) * 16;
    const signed char* ap = Xl + (size_t)(m0 + srow) * K + skq;
    const signed char* bp = Wl + (size_t)(n0 + srow) * K + skq;

    i4v acc[5][2][2] = {};   // level s = i+j-2

    i4v at[4], bt[4];
#pragma unroll
    for (int l = 0; l < 4; ++l) {
        at[l] = *(const i4v*)(ap + l * MK);
        bt[l] = *(const i4v*)(bp + l * NK);
    }

    for (int k0 = 0; k0 < K; k0 += 64) {
        __syncthreads();
#pragma unroll
        for (int l = 0; l < 4; ++l) {
            *(i4v*)&Asm[l][srow][skq] = at[l];
            *(i4v*)&Bsm[l][srow][skq] = bt[l];
        }
        __syncthreads();

        if (k0 + 64 < K) {
#pragma unroll
            for (int l = 0; l < 4; ++l) {
                at[l] = *(const i4v*)(ap + l * MK + k0 + 64);
                bt[l] = *(const i4v*)(bp + l * NK + k0 + 64);
            }
        }

        i4v bF[4][2];
#pragma unroll
        for (int j = 0; j < 4; ++j)
#pragma unroll
            for (int nt = 0; nt < 2; ++nt)
                bF[j][nt] = *(const i4v*)&Bsm[j][wn * 32 + nt * 16 + l16][quad * 16];

#pragma unroll
        for (int i = 0; i < 4; ++i) {
            i4v a0 = *(const i4v*)&Asm[i][wm * 32 +      l16][quad * 16];
            i4v a1 = *(const i4v*)&Asm[i][wm * 32 + 16 + l16][quad * 16];
#pragma unroll
            for (int j = 0; j < 4; ++j) {
                if (i + j < 2) continue;
                const int s = i + j - 2;
                acc[s][0][0] = __builtin_amdgcn_mfma_i32_16x16x64_i8(a0, bF[j][0], acc[s][0][0], 0, 0, 0);
                acc[s][0][1] = __builtin_amdgcn_mfma_i32_16x16x64_i8(a0, bF[j][1], acc[s][0][1], 0, 0, 0);
                acc[s][1][0] = __builtin_amdgcn_mfma_i32_16x16x64_i8(a1, bF[j][0], acc[s][1][0], 0, 0, 0);
                acc[s][1][1] = __builtin_amdgcn_mfma_i32_16x16x64_i8(a1, bF[j][1], acc[s][1][1], 0, 0, 0);
            }
        }
    }

    const double wt0 = ldexp(1.0, 16), wt1 = ldexp(1.0, 24), wt2 = ldexp(1.0, 32);
    const double wt3 = ldexp(1.0, 40), wt4 = ldexp(1.0, 48);
#pragma unroll
    for (int mt = 0; mt < 2; ++mt)
#pragma unroll
        for (int nt = 0; nt < 2; ++nt)
#pragma unroll
            for (int r = 0; r < 4; ++r) {
                int row = m0 + wm * 32 + mt * 16 + quad * 4 + r;
                int col = n0 + wn * 32 + nt * 16 + l16;
                double dsum = wt0 * (double)acc[0][mt][nt][r]
                            + wt1 * (double)acc[1][mt][nt][r]
                            + wt2 * (double)acc[2][mt][nt][r]
                            + wt3 * (double)acc[3][mt][nt][r]
                            + wt4 * (double)acc[4][mt][nt][r];
                C[(size_t)row * N + col] = dsum * xsc[row] * wsc[col] + (double)bias[col];
            }
}

// ------- V projection from precomputed bf16 hi/lo planes (bit-identical to R9 v64) -------
__global__ __launch_bounds__(256) void gemm_v64(
    const short* __restrict__ Ahp, const short* __restrict__ Alp,
    const short* __restrict__ Bhp, const short* __restrict__ Blp,
    const float* __restrict__ bias, float* __restrict__ C)
{
    const int K = 1024, N = 1024;
    __shared__ short Ah[64][40];
    __shared__ short Al[64][40];
    __shared__ short Bh[64][40];
    __shared__ short Bl[64][40];

    const int tid = threadIdx.x, lane = tid & 63, wave = tid >> 6;
    const int wm = wave >> 1, wn = wave & 1;
    const int quad = lane >> 4, l16 = lane & 15;
    const int m0 = blockIdx.y * 64, n0 = blockIdx.x * 64;
    const int srow = tid >> 2, sco = (tid & 3) * 8;
    const size_t aoff = (size_t)(m0 + srow) * K + sco;
    const size_t boff = (size_t)(n0 + srow) * K + sco;

    f4 acc[2][2] = {};
    for (int k0 = 0; k0 < K; k0 += 32) {
        s8v ah = *(const s8v*)(Ahp + aoff + k0);
        s8v al = *(const s8v*)(Alp + aoff + k0);
        s8v bh = *(const s8v*)(Bhp + boff + k0);
        s8v bl = *(const s8v*)(Blp + boff + k0);
        __syncthreads();
        *(s8v*)&Ah[srow][sco] = ah;
        *(s8v*)&Al[srow][sco] = al;
        *(s8v*)&Bh[srow][sco] = bh;
        *(s8v*)&Bl[srow][sco] = bl;
        __syncthreads();

        s8v af[2], afl[2], bf[2], bfl[2];
#pragma unroll
        for (int t = 0; t < 2; ++t) {
            af[t]  = *(s8v*)&Ah[wm * 32 + t * 16 + l16][quad * 8];
            afl[t] = *(s8v*)&Al[wm * 32 + t * 16 + l16][quad * 8];
            bf[t]  = *(s8v*)&Bh[wn * 32 + t * 16 + l16][quad * 8];
            bfl[t] = *(s8v*)&Bl[wn * 32 + t * 16 + l16][quad * 8];
        }
#pragma unroll
        for (int mt = 0; mt < 2; ++mt)
#pragma unroll
            for (int nt = 0; nt < 2; ++nt) {
                acc[mt][nt] = __builtin_amdgcn_mfma_f32_16x16x32_bf16(af[mt],  bf[nt],  acc[mt][nt], 0, 0, 0);
                acc[mt][nt] = __builtin_amdgcn_mfma_f32_16x16x32_bf16(af[mt],  bfl[nt], acc[mt][nt], 0, 0, 0);
                acc[mt][nt] = __builtin_amdgcn_mfma_f32_16x16x32_bf16(afl[mt], bf[nt],  acc[mt][nt], 0, 0, 0);
            }
    }
#pragma unroll
    for (int mt = 0; mt < 2; ++mt)
#pragma unroll
        for (int nt = 0; nt < 2; ++nt)
#pragma unroll
            for (int r = 0; r < 4; ++r) {
                int row = m0 + wm * 32 + mt * 16 + quad * 4 + r;
                int col = n0 + wn * 32 + nt * 16 + l16;
                C[(size_t)row * N + col] = acc[mt][nt][r] + bias[col];
            }
}

// ------- score GEMM: 64x64 tile, bf16 inputs, fp32 out (R8-proven) -------
__global__ __launch_bounds__(256) void gemm_score(
    const short* __restrict__ Qh, const short* __restrict__ Kh,
    float* __restrict__ C)
{
    const int K = 1024, N = 2048;
    __shared__ short As[64][40];
    __shared__ short Bs[64][40];
    const int tid = threadIdx.x, lane = tid & 63, wave = tid >> 6;
    const int wm = wave >> 1, wn = wave & 1;
    const int quad = lane >> 4, l16 = lane & 15;
    const int m0 = blockIdx.y * 64, n0 = blockIdx.x * 64;
    const int srow = tid >> 2, sco = (tid & 3) * 8;
    const short* ap = Qh + (size_t)(m0 + srow) * K + sco;
    const short* bp = Kh + (size_t)(n0 + srow) * K + sco;

    f4 acc[2][2] = {};
    for (int k0 = 0; k0 < K; k0 += 32) {
        s8v a8 = *(const s8v*)(ap + k0);
        s8v b8 = *(const s8v*)(bp + k0);
        __syncthreads();
        *(s8v*)&As[srow][sco] = a8;
        *(s8v*)&Bs[srow][sco] = b8;
        __syncthreads();
        s8v af[2], bf[2];
#pragma unroll
        for (int t = 0; t < 2; ++t) {
            af[t] = *(s8v*)&As[wm * 32 + t * 16 + l16][quad * 8];
            bf[t] = *(s8v*)&Bs[wn * 32 + t * 16 + l16][quad * 8];
        }
#pragma unroll
        for (int mt = 0; mt < 2; ++mt)
#pragma unroll
            for (int nt = 0; nt < 2; ++nt)
                acc[mt][nt] = __builtin_amdgcn_mfma_f32_16x16x32_bf16(
                    af[mt], bf[nt], acc[mt][nt], 0, 0, 0);
    }
#pragma unroll
    for (int mt = 0; mt < 2; ++mt)
#pragma unroll
        for (int nt = 0; nt < 2; ++nt)
#pragma unroll
            for (int r = 0; r < 4; ++r) {
                int row = m0 + wm * 32 + mt * 16 + quad * 4 + r;
                int col = n0 + wn * 32 + nt * 16 + l16;
                C[(size_t)row * N + col] = acc[mt][nt][r];
            }
}

// ------- fp64 L2 normalize + bf16 copy; y selects Q or K (R11-proven) -------
__global__ __launch_bounds__(256) void l2norm_f64bf16(
    double* __restrict__ dq, double* __restrict__ dk,
    short* __restrict__ hq, short* __restrict__ hk)
{
    double* d = blockIdx.y ? dk : dq;
    short*  h = blockIdx.y ? hk : hq;
    const int row = blockIdx.x;
    const int tid = threadIdx.x;
    double* p = d + (size_t)row * 1024 + tid * 4;
    double v0 = p[0], v1 = p[1], v2 = p[2], v3 = p[3];
    double s = v0 * v0 + v1 * v1 + v2 * v2 + v3 * v3;
#pragma unroll
    for (int off = 32; off > 0; off >>= 1) s += __shfl_down(s, off);
    __shared__ double ws[5];
    if ((tid & 63) == 0) ws[tid >> 6] = s;
    __syncthreads();
    if (tid == 0) ws[4] = fmax(sqrt(ws[0] + ws[1] + ws[2] + ws[3]), 1e-12);
    __syncthreads();
    double n = ws[4];
    double o0 = v0 / n, o1 = v1 / n, o2 = v2 / n, o3 = v3 / n;
    p[0] = o0; p[1] = o1; p[2] = o2; p[3] = o3;
    __align__(8) short hv[4] = {f2bf((float)o0), f2bf((float)o1),
                                f2bf((float)o2), f2bf((float)o3)};
    *(short4*)&h[(size_t)row * 1024 + tid * 4] = *(short4*)hv;
}

// ------- top-16 tournament argmax + fp64 rerank + route (R11-proven) -------
__global__ __launch_bounds__(256) void topk_route(
    const float*  __restrict__ S,
    const double* __restrict__ Qd,
    const double* __restrict__ Kd,
    const float*  __restrict__ Vf,
    float* __restrict__ routes_out,
    float* __restrict__ weights_out,
    float* __restrict__ feat_out,
    int batch)
{
    const int P = 2048, D = 1024;
    __shared__ float  sc[2048];
    __shared__ double qrow[1024];
    __shared__ float  wval[4];
    __shared__ int    widx[4];
    __shared__ int    gi_s;
    __shared__ int    cidx[16];
    __shared__ double cscore[16];
    __shared__ int    topi_s[8];
    __shared__ float  wts[8];

    const int p = blockIdx.x;
    const int tid = threadIdx.x;
    const int lane = tid & 63, wave = tid >> 6;

    const float4* sr4 = (const float4*)(S + (size_t)p * P);
    ((float4*)sc)[tid]       = sr4[tid];
    ((float4*)sc)[tid + 256] = sr4[tid + 256];
    {
        const double* q = Qd + (size_t)p * D + tid * 4;
        qrow[tid * 4 + 0] = q[0]; qrow[tid * 4 + 1] = q[1];
        qrow[tid * 4 + 2] = q[2]; qrow[tid * 4 + 3] = q[3];
    }
    __syncthreads();
    if (tid == 0) sc[p] = -1e30f;
    __syncthreads();

    float lv = -INFINITY; int li = 0x7fffffff;
#pragma unroll
    for (int r = 0; r < 8; ++r) {
        int j = tid + r * 256;
        float v = sc[j];
        if (v > lv || (v == lv && j < li)) { lv = v; li = j; }
    }

    for (int it = 0; it < 16; ++it) {
        float bv = lv; int bi = li;
#pragma unroll
        for (int off = 32; off > 0; off >>= 1) {
            float ov = __shfl_down(bv, off);
            int   oi = __shfl_down(bi, off);
            if (ov > bv || (ov == bv && oi < bi)) { bv = ov; bi = oi; }
        }
        if (lane == 0) { wval[wave] = bv; widx[wave] = bi; }
        __syncthreads();
        if (tid == 0) {
            float gv = wval[0]; int gi = widx[0];
#pragma unroll
            for (int w = 1; w < 4; ++w) {
                if (wval[w] > gv || (wval[w] == gv && widx[w] < gi)) {
                    gv = wval[w]; gi = widx[w];
                }
            }
            cidx[it] = gi; gi_s = gi;
            sc[gi] = -INFINITY;
        }
        __syncthreads();
        if ((gi_s & 255) == tid) {
            lv = -INFINITY; li = 0x7fffffff;
#pragma unroll
            for (int r = 0; r < 8; ++r) {
                int j = tid + r * 256;
                float v = sc[j];
                if (v > lv || (v == lv && j < li)) { lv = v; li = j; }
            }
        }
    }

    {
        const int cand = tid >> 4;
        const int l = tid & 15;
        const double* krow = Kd + (size_t)cidx[cand] * D;
        double s = 0.0;
#pragma unroll 8
        for (int j = 0; j < 64; ++j) {
            int e = l + j * 16;
            s = fma(qrow[e], krow[e], s);
        }
        s += __shfl_down(s, 8);
        s += __shfl_down(s, 4);
        s += __shfl_down(s, 2);
        s += __shfl_down(s, 1);
        if (l == 0) cscore[cand] = s;
    }
    __syncthreads();

    if (tid == 0) {
        unsigned used = 0;
        double tv[8]; int ti[8];
        for (int k = 0; k < 8; ++k) {
            int best = -1;
            for (int c = 0; c < 16; ++c) {
                if (used & (1u << c)) continue;
                if (best < 0 || cscore[c] > cscore[best] ||
                    (cscore[c] == cscore[best] && cidx[c] < cidx[best])) best = c;
            }
            used |= 1u << best;
            tv[k] = cscore[best]; ti[k] = cidx[best];
        }
        double m = tv[0], e[8], sum = 0.0;
        for (int k = 0; k < 8; ++k) { e[k] = exp((tv[k] - m) / TEMP); sum += e[k]; }
        const size_t row = (size_t)batch * P + p;
        for (int k = 0; k < 8; ++k) {
            float wk = (float)(e[k] / sum);
            wts[k] = wk; topi_s[k] = ti[k];
            routes_out[row * 8 + k]  = (float)ti[k];
            weights_out[row * 8 + k] = wk;
        }
    }
    __syncthreads();

    float4 a = {0.f, 0.f, 0.f, 0.f};
#pragma unroll
    for (int k = 0; k < 8; ++k) {
        const float4 v4 = ((const float4*)(Vf + (size_t)topi_s[k] * D))[tid];
        float wk = wts[k];
        a.x = fmaf(wk, v4.x, a.x);
        a.y = fmaf(wk, v4.y, a.y);
        a.z = fmaf(wk, v4.z, a.z);
        a.w = fmaf(wk, v4.w, a.w);
    }
    ((float4*)(feat_out + ((size_t)batch * P + p) * D))[tid] = a;
}

extern "C" void kernel_launch(void* const* d_in, const int* in_sizes, int n_in,
                              void* d_out, int out_size, void* d_ws, size_t ws_size,
                              hipStream_t stream)
{
    const float* x  = (const float*)d_in[0];  // (4,2049,1024)
    const float* Wq = (const float*)d_in[1];
    const float* bq = (const float*)d_in[2];
    const float* Wk = (const float*)d_in[3];
    const float* bk = (const float*)d_in[4];
    const float* Wv = (const float*)d_in[5];
    const float* bv = (const float*)d_in[6];

    const int B = 4, P = 2048, D = 1024;
    const size_t PD = (size_t)P * D;
    const size_t DD = (size_t)D * D;

    double* Qd   = (double*)d_ws;             // P*D f64
    double* Kd   = Qd + PD;
    double* xsc  = Kd + PD;                   // 2048
    double* wqsc = xsc + 2048;                // 1024
    double* wksc = wqsc + 1024;               // 1024
    short*  Qh   = (short*)(wksc + 1024);     // P*D bf16
    short*  Kh   = Qh + PD;
    short*  xh   = Kh + PD;                   // x bf16 hi
    short*  xlo  = xh + PD;                   // x bf16 lo
    short*  Wvh  = xlo + PD;                  // Wv bf16 hi
    short*  Wvl  = Wvh + DD;                  // Wv bf16 lo
    float*  Vf   = (float*)(Wvl + DD);        // P*D f32
    float*  Sf   = Vf + PD;                   // P*P f32
    signed char* Xl  = (signed char*)(Sf + (size_t)P * P);  // 4*P*D
    signed char* Wql = Xl + 4 * PD;                          // 4*D*D
    signed char* Wkl = Wql + 4 * DD;

    float* out     = (float*)d_out;
    float* routes  = out;
    float* weights = out + (size_t)B * P * 8;
    float* feat    = out + (size_t)B * P * 16;

    dim3 blk(256);
    quantize_rows<<<dim3(1024), blk, 0, stream>>>(Wq, Wql, (long)DD, wqsc);
    quantize_rows<<<dim3(1024), blk, 0, stream>>>(Wk, Wkl, (long)DD, wksc);
    tobf16_split<<<dim3(1024), blk, 0, stream>>>(Wv, Wvh, Wvl);

    for (int b = 0; b < B; ++b) {
        const float* xb = x + ((size_t)b * 2049 + 1) * D;  // rows 1..2048 contiguous
        quantize_rows<<<dim3(P), blk, 0, stream>>>(xb, Xl, (long)PD, xsc);
        tobf16_split<<<dim3(P), blk, 0, stream>>>(xb, xh, xlo);
        gemm_i8qk<<<dim3(16, 32, 2), blk, 0, stream>>>(Xl, Wql, Wkl, xsc, wqsc, wksc,
                                                       bq, bk, Qd, Kd);
        gemm_v64<<<dim3(16, 32), blk, 0, stream>>>(xh, xlo, Wvh, Wvl, bv, Vf);
        l2norm_f64bf16<<<dim3(P, 2), blk, 0, stream>>>(Qd, Kd, Qh, Kh);
        gemm_score<<<dim3(32, 32), blk, 0, stream>>>(Qh, Kh, Sf);
        topk_route<<<dim3(P), blk, 0, stream>>>(Sf, Qd, Kd, Vf, routes, weights, feat, b);
    }
}